// Round 16
// baseline (208.369 us; speedup 1.0000x reference)
//
#include <hip/hip_runtime.h>
#include <hip/hip_bf16.h>

// Problem constants
#define TT   512
#define DD   64
#define NWK  4
#define STP  16
#define NPJ  15          // others per w
#define NBLK 60          // NWK * NPJ
#define CMAT (TT * TT)   // floats per cost matrix
// u-domain scale: u = R / (gamma * ln2), gamma = 5
#define CSCALE 0.2885390081777927f
#define USCALE 3.4657359027997265f   // gamma * ln2
#define BIGC   2.885390081777927e8f  // 1e9 * CSCALE

#define SA 132   // LDS leading stride (128 + 4 pad)

// ---------------------------------------------------------------------------
// Kernel 1: cost matrices, scaled by CSCALE. 128x128 tile per block, 256 thr,
// split 4+4 register tile per thread (rows {r0..r0+3, r0+64..67} x cols same)
// so every ds_read_b128 is <=2-way bank-aliased (free). grid (4,4,n).
// ---------------------------------------------------------------------------
__global__ __launch_bounds__(256) void cost_kernel(const float* __restrict__ data,
                                                   const int* __restrict__ lens,
                                                   float* __restrict__ cost, int base) {
  int blk = base + blockIdx.z;
  int w = blk / NPJ, j = blk - w * NPJ;
  int la = lens[w * STP];
  int lb = lens[w * STP + 1 + j];
  int ti = blockIdx.y, tj = blockIdx.x;
  if (ti * 128 >= la || tj * 128 >= lb) return;

  __shared__ float As[DD][SA];   // k-major: As[k][r], r in [0,128)
  __shared__ float Bs[DD][SA];
  __shared__ float a2[128], b2[128];

  const float* A = data + ((size_t)(w * STP) * TT + (size_t)ti * 128) * DD;
  const float* B = data + ((size_t)(w * STP + 1 + j) * TT + (size_t)tj * 128) * DD;
  int t = threadIdx.x;

  #pragma unroll
  for (int i = 0; i < 8; ++i) {
    int idx = t + i * 256;        // [0, 2048)
    int r = idx & 127;            // row within tile
    int kq = idx >> 7;            // float4 index along k, [0,16)
    float4 va = *(const float4*)(A + r * DD + kq * 4);
    As[kq * 4 + 0][r] = va.x; As[kq * 4 + 1][r] = va.y;
    As[kq * 4 + 2][r] = va.z; As[kq * 4 + 3][r] = va.w;
    float4 vb = *(const float4*)(B + r * DD + kq * 4);
    Bs[kq * 4 + 0][r] = vb.x; Bs[kq * 4 + 1][r] = vb.y;
    Bs[kq * 4 + 2][r] = vb.z; Bs[kq * 4 + 3][r] = vb.w;
  }
  __syncthreads();
  if (t < 128) {
    float s = 0.f;
    for (int k = 0; k < DD; ++k) { float x = As[k][t]; s += x * x; }
    a2[t] = s;
  } else {
    float s = 0.f;
    for (int k = 0; k < DD; ++k) { float x = Bs[k][t - 128]; s += x * x; }
    b2[t - 128] = s;
  }
  __syncthreads();

  int r0 = (t >> 4) << 2;   // {0,4,...,60}
  int c0 = (t & 15) << 2;   // {0,4,...,60}
  float acc[8][8];
  #pragma unroll
  for (int i = 0; i < 8; ++i)
    #pragma unroll
    for (int q = 0; q < 8; ++q) acc[i][q] = 0.f;

  #pragma unroll 2
  for (int k = 0; k < DD; ++k) {
    float4 aL = *(const float4*)&As[k][r0];
    float4 aH = *(const float4*)&As[k][r0 + 64];
    float4 bL = *(const float4*)&Bs[k][c0];
    float4 bH = *(const float4*)&Bs[k][c0 + 64];
    float a[8] = {aL.x, aL.y, aL.z, aL.w, aH.x, aH.y, aH.z, aH.w};
    float b[8] = {bL.x, bL.y, bL.z, bL.w, bH.x, bH.y, bH.z, bH.w};
    #pragma unroll
    for (int i = 0; i < 8; ++i)
      #pragma unroll
      for (int q = 0; q < 8; ++q)
        acc[i][q] += a[i] * b[q];
  }

  float* Cbase = cost + (size_t)blockIdx.z * CMAT;
  #pragma unroll
  for (int i = 0; i < 8; ++i) {
    int rr = (i < 4) ? (r0 + i) : (r0 + 60 + i);   // r0+64+(i-4)
    float ar = a2[rr];
    float* Crow = Cbase + (size_t)(ti * 128 + rr) * TT + tj * 128;
    float4 o;
    o.x = (ar + b2[c0 + 0] - 2.f * acc[i][0]) * CSCALE;
    o.y = (ar + b2[c0 + 1] - 2.f * acc[i][1]) * CSCALE;
    o.z = (ar + b2[c0 + 2] - 2.f * acc[i][2]) * CSCALE;
    o.w = (ar + b2[c0 + 3] - 2.f * acc[i][3]) * CSCALE;
    *(float4*)(Crow + c0) = o;
    float4 o2;
    o2.x = (ar + b2[c0 + 64] - 2.f * acc[i][4]) * CSCALE;
    o2.y = (ar + b2[c0 + 65] - 2.f * acc[i][5]) * CSCALE;
    o2.z = (ar + b2[c0 + 66] - 2.f * acc[i][6]) * CSCALE;
    o2.w = (ar + b2[c0 + 67] - 2.f * acc[i][7]) * CSCALE;
    *(float4*)(Crow + c0 + 64) = o2;
  }
}

// ---------------------------------------------------------------------------
// Soft-DTW DP cell in u-units: u = dc + min - log2(1 + 2^(min-med) + 2^(min-max))
// ---------------------------------------------------------------------------
__device__ __forceinline__ float dpcell(float dc, float a, float b, float c) {
  float mn = fminf(fminf(a, b), c);
  float mx = fmaxf(fmaxf(a, b), c);
  float md = __builtin_amdgcn_fmed3f(a, b, c);
  float e = 1.0f + __builtin_amdgcn_exp2f(mn - md) + __builtin_amdgcn_exp2f(mn - mx);
  return dc + mn - __builtin_amdgcn_logf(e);
}

// DPP wave_shr:1 — VALU-latency replacement for __shfl_up(x, 1).
// Lanes 1..63 receive lane-1's value; lane 0 keeps its own (bound_ctrl=false),
// which matches __shfl_up semantics (lane 0 is overwritten by caller anyway).
__device__ __forceinline__ float wave_shr1(float x) {
  int xi = __float_as_int(x);
  int r = __builtin_amdgcn_update_dpp(xi, xi, 0x138 /*wave_shr:1*/, 0xF, 0xF, false);
  return __int_as_float(r);
}

// ---------------------------------------------------------------------------
// Kernel 2: fused DP (blocks [0,ndp)) + gram (blocks [ndp, ndp+121)).
// DP: barrier-free systolic pipeline — round-15 champion structure (4 waves;
// wave q owns cols [128q,128q+128); lane owns 2 cols, lane-skew 1 row/lane;
// DPP intra-wave boundary; write-once LDS column + spin flags inter-wave;
// fill/STEADY/drain split removing the act guard from steady groups).
// NEW instruction diet in STEADY (g in [8,62)) — with ~1 wave/SIMD, issue
// count adds directly to the serial step time:
//  (a) flag publish hoisted out of the k-loop: for ln==63 in steady,
//      (r&7)==0 holds exactly at k=7 with flag value 8g-55 (compile-time
//      expression). Per-k bufB stores remain; 8 runtime tests -> 1 publish.
//  (b) clamp-free prefetch: rr = 8(g+1)+k-ln is in [9,511] for g in [8,62)
//      (min 8*9+0-63=9, max 8*62+15-0=511) -> both clamps provably dead;
//      one row-base pointer + stride loads replaces per-k add+2clamp+lshl.
// Groups 62..ngrp fall to the guarded path (unchanged). Arithmetic and
// protocol values bit-identical to round 15.
// ---------------------------------------------------------------------------
__global__ __launch_bounds__(256) void dp_gram_kernel(const float* __restrict__ cost,
                                                      const int* __restrict__ lens,
                                                      const float* __restrict__ data,
                                                      float* __restrict__ sdt,
                                                      float* __restrict__ gram,
                                                      int base, int ndp) {
  int bid = blockIdx.x;

  if (bid >= ndp) {
    // ---------------- gram path: 44x44 Gram over K = 32768 ----------------
    __shared__ float red[4][16];
    int g = bid - ndp;
    int bx = g / 11, by = g - bx * 11;
    int t = threadIdx.x;
    const float* Ar[4]; const float* Br[4];
    #pragma unroll
    for (int a = 0; a < 4; ++a) {
      int gx = bx * 4 + a;
      Ar[a] = data + (size_t)((gx / 11) * STP + gx % 11) * (TT * DD);
      int gy = by * 4 + a;
      Br[a] = data + (size_t)((gy / 11) * STP + gy % 11) * (TT * DD);
    }
    float acc[4][4];
    #pragma unroll
    for (int a = 0; a < 4; ++a)
      #pragma unroll
      for (int b = 0; b < 4; ++b) acc[a][b] = 0.f;
    for (int k = t * 4; k < TT * DD; k += 1024) {
      float4 av[4], bv[4];
      #pragma unroll
      for (int a = 0; a < 4; ++a) av[a] = *(const float4*)(Ar[a] + k);
      #pragma unroll
      for (int b = 0; b < 4; ++b) bv[b] = *(const float4*)(Br[b] + k);
      #pragma unroll
      for (int a = 0; a < 4; ++a)
        #pragma unroll
        for (int b = 0; b < 4; ++b)
          acc[a][b] += av[a].x * bv[b].x + av[a].y * bv[b].y +
                       av[a].z * bv[b].z + av[a].w * bv[b].w;
    }
    int wave = t >> 6, lane = t & 63;
    #pragma unroll
    for (int a = 0; a < 4; ++a)
      #pragma unroll
      for (int b = 0; b < 4; ++b) {
        float v = acc[a][b];
        for (int off = 32; off > 0; off >>= 1) v += __shfl_down(v, off);
        if (lane == 0) red[wave][a * 4 + b] = v;
      }
    __syncthreads();
    if (t < 16) {
      float v = red[0][t] + red[1][t] + red[2][t] + red[3][t];
      int a = t >> 2, b = t & 3;
      gram[(size_t)(bx * 4 + a) * 44 + by * 4 + b] = v;
    }
    return;
  }

  // -------------------------- DP path --------------------------
  __shared__ float bufB[3][600];   // boundary column per wave (write-once)
  __shared__ int flags[4];

  if (threadIdx.x < 4) flags[threadIdx.x] = 0;
  __syncthreads();

  int blk = base + bid;
  int w = blk / NPJ, j = blk - w * NPJ;
  int la = lens[w * STP];
  int lb = lens[w * STP + 1 + j];
  const float* C = cost + (size_t)bid * CMAT;

  int q = threadIdx.x >> 6, ln = threadIdx.x & 63;
  int c0 = q * 128 + ln * 2;
  const float* Cp = C + c0;

  // target cell (la-1, lb-1)
  int qt = (lb - 1) >> 7;
  int lt = ((lb - 1) >> 1) & 63;
  int par = (lb - 1) & 1;
  int rt = la - 1;
  bool isT = (q == qt) && (ln == lt);

  float U0 = BIGC, U1 = BIGC;          // own cols, previous row
  float NL = BIGC;                     // left neighbor value, current row
  float NLd = (q == 0 && ln == 0) ? 0.0f : BIGC;  // left-diag (prev row)
  float v1s = BIGC;                    // last computed right-col value
  float res = 0.0f;

  int ngrp = (la + 70) >> 3;

  // cost regs: cc = current group (rows 8g+k-ln), cn = next group prefetch
  float2 cc[8], cn[8];
  #pragma unroll
  for (int k = 0; k < 8; ++k) {
    int rr = k - ln; rr = rr < 0 ? 0 : (rr > 511 ? 511 : rr);
    cc[k] = *(const float2*)(Cp + (size_t)rr * TT);
  }
  float bb[8];

  for (int g = 0; g < ngrp; ++g) {
    if (q > 0) {
      int need = 8 * g + 9; if (need > la) need = la;
      while (*(volatile int*)&flags[q - 1] < need) __builtin_amdgcn_s_sleep(1);
      asm volatile("s_waitcnt lgkmcnt(0)" ::: "memory");
      #pragma unroll
      for (int k = 0; k < 8; ++k) bb[k] = bufB[q - 1][8 * g + 1 + k];
      if (g == 0) {
        float nl0 = bufB[q - 1][0];
        if (ln == 0) NL = nl0;
      }
    }
    if (g >= 8 && g < 62) {
      // ---- STEADY: r in [1,511] for every lane; prefetch rows in [9,511] ----
      // clamp-free prefetch via row-base pointer (no per-k clamps)
      const float* Pn = Cp + (size_t)(8 * (g + 1) - ln) * TT;
      #pragma unroll
      for (int k = 0; k < 8; ++k) cn[k] = *(const float2*)(Pn + (size_t)k * TT);
      #pragma unroll
      for (int k = 0; k < 8; ++k) {
        int r = 8 * g + k - ln;
        float v0 = dpcell(cc[k].x, NLd, U0, NL);
        float v1 = dpcell(cc[k].y, U0, U1, v0);
        if (isT & (r == rt)) res = par ? v1 : v0;
        NLd = NL; U0 = v0; U1 = v1; v1s = v1;
        if (q < 3 && ln == 63) bufB[q][r] = v1;   // write-once row store
        float nb = wave_shr1(v1s);
        if (ln == 0) nb = (q == 0) ? BIGC : bb[k];
        NL = nb;
      }
      // publish once per group: for ln==63, (r&7)==0 holds exactly at k=7,
      // r = 8g-56 -> flag = 8g-55 (same value/order as per-k variant)
      if (q < 3 && ln == 63) {
        asm volatile("s_waitcnt lgkmcnt(0)" ::: "memory");
        *(volatile int*)&flags[q] = 8 * g - 55;
      }
    } else {
      // ---- fill / drain: per-lane act guard + clamped prefetch ----
      #pragma unroll
      for (int k = 0; k < 8; ++k) {
        int rr = 8 * (g + 1) + k - ln; rr = rr < 0 ? 0 : (rr > 511 ? 511 : rr);
        cn[k] = *(const float2*)(Cp + (size_t)rr * TT);
      }
      #pragma unroll
      for (int k = 0; k < 8; ++k) {
        int r = 8 * g + k - ln;
        bool act = ((unsigned)r < 512u);
        if (act) {
          float v0 = dpcell(cc[k].x, NLd, U0, NL);
          float v1 = dpcell(cc[k].y, U0, U1, v0);
          if (isT & (r == rt)) res = par ? v1 : v0;
          NLd = NL; U0 = v0; U1 = v1; v1s = v1;
          if (q < 3 && ln == 63) {
            bufB[q][r] = v1;
            if ((r & 7) == 0) {
              asm volatile("s_waitcnt lgkmcnt(0)" ::: "memory");
              *(volatile int*)&flags[q] = r + 1;
            }
          }
        }
        float nb = wave_shr1(v1s);
        if (ln == 0) nb = (q == 0) ? BIGC : bb[k];
        NL = nb;
      }
    }
    #pragma unroll
    for (int k = 0; k < 8; ++k) cc[k] = cn[k];
  }
  if (q < 3 && ln == 63) {
    asm volatile("s_waitcnt lgkmcnt(0)" ::: "memory");
    *(volatile int*)&flags[q] = 512;   // release any remaining pollers
  }
  if (isT) sdt[blk] = res * USCALE;
}

// ---------------------------------------------------------------------------
// Kernel 4: final combine. block 640 = 10 waves; waves 0..8: one MMD pair each;
// wave 9: triplet losses; thread 0 writes the scalar.
// ---------------------------------------------------------------------------
__global__ __launch_bounds__(640) void final_kernel(const float* __restrict__ sdt,
                                                    const int* __restrict__ lens,
                                                    const float* __restrict__ gram,
                                                    float* __restrict__ out) {
  __shared__ float partial[16];
  int t = threadIdx.x, wave = t >> 6, lane = t & 63;
  if (wave < 9) {
    const int piA[9] = {0, 0, 0, 1, 1, 2, 2, 3, 3};
    const int pjA[9] = {1, 2, 3, 2, 3, 1, 3, 1, 2};
    int P = piA[wave], Q = pjA[wave];
    float s1 = 0.f;
    for (int c = lane; c < 484; c += 64) {
      int i = c / 22, jj = c - (c / 22) * 22;
      int gi = (i < 11) ? P * 11 + i : Q * 11 + (i - 11);
      int gj = (jj < 11) ? P * 11 + jj : Q * 11 + (jj - 11);
      s1 += gram[gi * 44 + gi] + gram[gj * 44 + gj] - 2.f * gram[gi * 44 + gj];
    }
    for (int off = 32; off > 0; off >>= 1) s1 += __shfl_down(s1, off);
    s1 = __shfl(s1, 0);
    float bw = s1 / 462.0f * 0.25f;     // /(ns^2-ns) then / KMUL^(KNUM//2)=4
    float inv[5];
    float b = bw;
    #pragma unroll
    for (int qq = 0; qq < 5; ++qq) { inv[qq] = -1.0f / b; b *= 2.0f; }
    float s2 = 0.f;
    for (int c = lane; c < 484; c += 64) {
      int i = c / 22, jj = c - (c / 22) * 22;
      int gi = (i < 11) ? P * 11 + i : Q * 11 + (i - 11);
      int gj = (jj < 11) ? P * 11 + jj : Q * 11 + (jj - 11);
      float l2 = gram[gi * 44 + gi] + gram[gj * 44 + gj] - 2.f * gram[gi * 44 + gj];
      float kk = 0.f;
      #pragma unroll
      for (int qq = 0; qq < 5; ++qq) kk += __expf(l2 * inv[qq]);
      float sgn = ((i < 11) == (jj < 11)) ? 1.0f : -1.0f;
      s2 += sgn * kk;
    }
    for (int off = 32; off > 0; off >>= 1) s2 += __shfl_down(s2, off);
    if (lane == 0) partial[wave] = s2 / 121.0f;
  } else {
    float term = 0.f;
    if (wave == 9 && lane < 4) {
      int w = lane;
      float L0 = (float)lens[w * STP];
      float dist[15];
      for (int qq = 0; qq < 15; ++qq)
        dist[qq] = sdt[w * NPJ + qq] / (L0 + (float)lens[w * STP + 1 + qq]);
      float ca = 0.f, cb = 0.f;
      for (int a = 0; a < 6; ++a) ca += dist[a];
      ca *= (1.0f / 6.0f);
      for (int bq = 6; bq < 11; ++bq) cb += dist[bq];
      cb *= (1.0f / 5.0f);
      float lksum = 0.f; int nz = 0;
      for (int a = 0; a < 6; ++a)
        for (int bq = 6; bq < 15; ++bq) {
          float x = dist[a] + 1.0f - dist[bq];   // MARGIN = 1.0
          if (x > 0.f) { lksum += x; nz += 1; }
        }
      float intra = 0.f;
      for (int a = 0; a < 6; ++a) intra += dist[a] - ca;
      float inter = fmaxf(0.f, 1.0f - fabsf(ca - cb));  // BETA = 1.0
      term = lksum / (float)(nz + 1) + intra * 0.1f + inter * 0.1f;  // P=R=0.1
    }
    if (wave == 9) {
      term += __shfl_down(term, 1);
      term += __shfl_down(term, 2);
      if (lane == 0) partial[9] = term * 0.25f;   // mean over NW=4
    }
  }
  __syncthreads();
  if (t == 0) {
    float mx = 0.0f;                               // zero-pad in the max
    for (int p = 0; p < 9; ++p) mx = fmaxf(mx, partial[p]);
    out[0] = partial[9] + 0.01f * mx;              // ALPHA = 0.01
  }
}

// ---------------------------------------------------------------------------
extern "C" void kernel_launch(void* const* d_in, const int* in_sizes, int n_in,
                              void* d_out, int out_size, void* d_ws, size_t ws_size,
                              hipStream_t stream) {
  const float* data = (const float*)d_in[0];
  const int* lens = (const int*)d_in[1];
  float* out = (float*)d_out;

  float* sdtb  = (float*)d_ws;                      // 60 floats
  float* gramb = sdtb + 64;                         // 44*44 floats
  float* costb = (float*)((char*)d_ws + 8192);      // cost chunks

  size_t avail = (ws_size > 8192) ? (ws_size - 8192) : 0;
  int chunk = (int)(avail / ((size_t)CMAT * sizeof(float)));
  if (chunk < 1) chunk = 1;
  if (chunk > NBLK) chunk = NBLK;

  bool first = true;
  for (int base = 0; base < NBLK; base += chunk) {
    int n = NBLK - base;
    if (n > chunk) n = chunk;
    cost_kernel<<<dim3(4, 4, n), 256, 0, stream>>>(data, lens, costb, base);
    int extra = first ? 121 : 0;   // fuse gram onto otherwise-idle CUs
    dp_gram_kernel<<<n + extra, 256, 0, stream>>>(costb, lens, data, sdtb, gramb, base, n);
    first = false;
  }
  final_kernel<<<1, 640, 0, stream>>>(sdtb, lens, gramb, out);
}

// Round 17
// 195.438 us; speedup vs baseline: 1.0662x; 1.0662x over previous
//
#include <hip/hip_runtime.h>
#include <hip/hip_bf16.h>

// Problem constants
#define TT   512
#define DD   64
#define NWK  4
#define STP  16
#define NPJ  15          // others per w
#define NBLK 60          // NWK * NPJ
#define CMAT (TT * TT)   // floats per cost matrix
// u-domain scale: u = R / (gamma * ln2), gamma = 5
#define CSCALE 0.2885390081777927f
#define USCALE 3.4657359027997265f   // gamma * ln2
#define BIGC   2.885390081777927e8f  // 1e9 * CSCALE

#define SA 132   // LDS leading stride (128 + 4 pad)

// ---------------------------------------------------------------------------
// Kernel 1: cost matrices, scaled by CSCALE. 128x128 tile per block, 256 thr,
// split 4+4 register tile per thread (rows {r0..r0+3, r0+64..67} x cols same)
// so every ds_read_b128 is <=2-way bank-aliased (free). grid (4,4,n).
// ---------------------------------------------------------------------------
__global__ __launch_bounds__(256) void cost_kernel(const float* __restrict__ data,
                                                   const int* __restrict__ lens,
                                                   float* __restrict__ cost, int base) {
  int blk = base + blockIdx.z;
  int w = blk / NPJ, j = blk - w * NPJ;
  int la = lens[w * STP];
  int lb = lens[w * STP + 1 + j];
  int ti = blockIdx.y, tj = blockIdx.x;
  if (ti * 128 >= la || tj * 128 >= lb) return;

  __shared__ float As[DD][SA];   // k-major: As[k][r], r in [0,128)
  __shared__ float Bs[DD][SA];
  __shared__ float a2[128], b2[128];

  const float* A = data + ((size_t)(w * STP) * TT + (size_t)ti * 128) * DD;
  const float* B = data + ((size_t)(w * STP + 1 + j) * TT + (size_t)tj * 128) * DD;
  int t = threadIdx.x;

  #pragma unroll
  for (int i = 0; i < 8; ++i) {
    int idx = t + i * 256;        // [0, 2048)
    int r = idx & 127;            // row within tile
    int kq = idx >> 7;            // float4 index along k, [0,16)
    float4 va = *(const float4*)(A + r * DD + kq * 4);
    As[kq * 4 + 0][r] = va.x; As[kq * 4 + 1][r] = va.y;
    As[kq * 4 + 2][r] = va.z; As[kq * 4 + 3][r] = va.w;
    float4 vb = *(const float4*)(B + r * DD + kq * 4);
    Bs[kq * 4 + 0][r] = vb.x; Bs[kq * 4 + 1][r] = vb.y;
    Bs[kq * 4 + 2][r] = vb.z; Bs[kq * 4 + 3][r] = vb.w;
  }
  __syncthreads();
  if (t < 128) {
    float s = 0.f;
    for (int k = 0; k < DD; ++k) { float x = As[k][t]; s += x * x; }
    a2[t] = s;
  } else {
    float s = 0.f;
    for (int k = 0; k < DD; ++k) { float x = Bs[k][t - 128]; s += x * x; }
    b2[t - 128] = s;
  }
  __syncthreads();

  int r0 = (t >> 4) << 2;   // {0,4,...,60}
  int c0 = (t & 15) << 2;   // {0,4,...,60}
  float acc[8][8];
  #pragma unroll
  for (int i = 0; i < 8; ++i)
    #pragma unroll
    for (int q = 0; q < 8; ++q) acc[i][q] = 0.f;

  #pragma unroll 2
  for (int k = 0; k < DD; ++k) {
    float4 aL = *(const float4*)&As[k][r0];
    float4 aH = *(const float4*)&As[k][r0 + 64];
    float4 bL = *(const float4*)&Bs[k][c0];
    float4 bH = *(const float4*)&Bs[k][c0 + 64];
    float a[8] = {aL.x, aL.y, aL.z, aL.w, aH.x, aH.y, aH.z, aH.w};
    float b[8] = {bL.x, bL.y, bL.z, bL.w, bH.x, bH.y, bH.z, bH.w};
    #pragma unroll
    for (int i = 0; i < 8; ++i)
      #pragma unroll
      for (int q = 0; q < 8; ++q)
        acc[i][q] += a[i] * b[q];
  }

  float* Cbase = cost + (size_t)blockIdx.z * CMAT;
  #pragma unroll
  for (int i = 0; i < 8; ++i) {
    int rr = (i < 4) ? (r0 + i) : (r0 + 60 + i);   // r0+64+(i-4)
    float ar = a2[rr];
    float* Crow = Cbase + (size_t)(ti * 128 + rr) * TT + tj * 128;
    float4 o;
    o.x = (ar + b2[c0 + 0] - 2.f * acc[i][0]) * CSCALE;
    o.y = (ar + b2[c0 + 1] - 2.f * acc[i][1]) * CSCALE;
    o.z = (ar + b2[c0 + 2] - 2.f * acc[i][2]) * CSCALE;
    o.w = (ar + b2[c0 + 3] - 2.f * acc[i][3]) * CSCALE;
    *(float4*)(Crow + c0) = o;
    float4 o2;
    o2.x = (ar + b2[c0 + 64] - 2.f * acc[i][4]) * CSCALE;
    o2.y = (ar + b2[c0 + 65] - 2.f * acc[i][5]) * CSCALE;
    o2.z = (ar + b2[c0 + 66] - 2.f * acc[i][6]) * CSCALE;
    o2.w = (ar + b2[c0 + 67] - 2.f * acc[i][7]) * CSCALE;
    *(float4*)(Crow + c0 + 64) = o2;
  }
}

// ---------------------------------------------------------------------------
// Soft-DTW DP cell in u-units: u = dc + min - log2(1 + 2^(min-med) + 2^(min-max))
// ---------------------------------------------------------------------------
__device__ __forceinline__ float dpcell(float dc, float a, float b, float c) {
  float mn = fminf(fminf(a, b), c);
  float mx = fmaxf(fmaxf(a, b), c);
  float md = __builtin_amdgcn_fmed3f(a, b, c);
  float e = 1.0f + __builtin_amdgcn_exp2f(mn - md) + __builtin_amdgcn_exp2f(mn - mx);
  return dc + mn - __builtin_amdgcn_logf(e);
}

// DPP wave_shr:1 — VALU-latency replacement for __shfl_up(x, 1).
// Lanes 1..63 receive lane-1's value; lane 0 keeps its own (bound_ctrl=false),
// which matches __shfl_up semantics (lane 0 is overwritten by caller anyway).
__device__ __forceinline__ float wave_shr1(float x) {
  int xi = __float_as_int(x);
  int r = __builtin_amdgcn_update_dpp(xi, xi, 0x138 /*wave_shr:1*/, 0xF, 0xF, false);
  return __int_as_float(r);
}

// ---------------------------------------------------------------------------
// Kernel 2: fused DP (blocks [0,ndp)) + gram (blocks [ndp, ndp+121)).
// DP: barrier-free systolic pipeline — round-11 champion structure (4 waves;
// wave q owns cols [128q,128q+128); lane owns 2 cols, lane-skew 1 row/lane;
// DPP intra-wave boundary; write-once LDS column + spin flags inter-wave;
// publish at (r&7)==0 -> flag 8g+9 meets need exactly; lgkm-only fences).
// The group loop is split fill (g<8) / STEADY (8<=g<64) / drain.
// In steady groups every lane has r = 8g+k-ln in [1,511] -> the per-lane
// divergent `act` guard is provably all-true; the steady body drops it,
// removing vcmp+saveexec+cbranch serialization from ~78% of the ~576 steps
// of this latency-bound chain. Per-cell arithmetic identical -> bit-identical.
// (Round-16's further "instruction diet" — hoisted publish + clamp-free
// prefetch — REGRESSED dp 103->116: the compiler's schedule here is a local
// optimum; reverted to this verified champion.)
// ---------------------------------------------------------------------------
__global__ __launch_bounds__(256) void dp_gram_kernel(const float* __restrict__ cost,
                                                      const int* __restrict__ lens,
                                                      const float* __restrict__ data,
                                                      float* __restrict__ sdt,
                                                      float* __restrict__ gram,
                                                      int base, int ndp) {
  int bid = blockIdx.x;

  if (bid >= ndp) {
    // ---------------- gram path: 44x44 Gram over K = 32768 ----------------
    __shared__ float red[4][16];
    int g = bid - ndp;
    int bx = g / 11, by = g - bx * 11;
    int t = threadIdx.x;
    const float* Ar[4]; const float* Br[4];
    #pragma unroll
    for (int a = 0; a < 4; ++a) {
      int gx = bx * 4 + a;
      Ar[a] = data + (size_t)((gx / 11) * STP + gx % 11) * (TT * DD);
      int gy = by * 4 + a;
      Br[a] = data + (size_t)((gy / 11) * STP + gy % 11) * (TT * DD);
    }
    float acc[4][4];
    #pragma unroll
    for (int a = 0; a < 4; ++a)
      #pragma unroll
      for (int b = 0; b < 4; ++b) acc[a][b] = 0.f;
    for (int k = t * 4; k < TT * DD; k += 1024) {
      float4 av[4], bv[4];
      #pragma unroll
      for (int a = 0; a < 4; ++a) av[a] = *(const float4*)(Ar[a] + k);
      #pragma unroll
      for (int b = 0; b < 4; ++b) bv[b] = *(const float4*)(Br[b] + k);
      #pragma unroll
      for (int a = 0; a < 4; ++a)
        #pragma unroll
        for (int b = 0; b < 4; ++b)
          acc[a][b] += av[a].x * bv[b].x + av[a].y * bv[b].y +
                       av[a].z * bv[b].z + av[a].w * bv[b].w;
    }
    int wave = t >> 6, lane = t & 63;
    #pragma unroll
    for (int a = 0; a < 4; ++a)
      #pragma unroll
      for (int b = 0; b < 4; ++b) {
        float v = acc[a][b];
        for (int off = 32; off > 0; off >>= 1) v += __shfl_down(v, off);
        if (lane == 0) red[wave][a * 4 + b] = v;
      }
    __syncthreads();
    if (t < 16) {
      float v = red[0][t] + red[1][t] + red[2][t] + red[3][t];
      int a = t >> 2, b = t & 3;
      gram[(size_t)(bx * 4 + a) * 44 + by * 4 + b] = v;
    }
    return;
  }

  // -------------------------- DP path --------------------------
  __shared__ float bufB[3][600];   // boundary column per wave (write-once)
  __shared__ int flags[4];

  if (threadIdx.x < 4) flags[threadIdx.x] = 0;
  __syncthreads();

  int blk = base + bid;
  int w = blk / NPJ, j = blk - w * NPJ;
  int la = lens[w * STP];
  int lb = lens[w * STP + 1 + j];
  const float* C = cost + (size_t)bid * CMAT;

  int q = threadIdx.x >> 6, ln = threadIdx.x & 63;
  int c0 = q * 128 + ln * 2;
  const float* Cp = C + c0;

  // target cell (la-1, lb-1)
  int qt = (lb - 1) >> 7;
  int lt = ((lb - 1) >> 1) & 63;
  int par = (lb - 1) & 1;
  int rt = la - 1;
  bool isT = (q == qt) && (ln == lt);

  float U0 = BIGC, U1 = BIGC;          // own cols, previous row
  float NL = BIGC;                     // left neighbor value, current row
  float NLd = (q == 0 && ln == 0) ? 0.0f : BIGC;  // left-diag (prev row)
  float v1s = BIGC;                    // last computed right-col value
  float res = 0.0f;

  int ngrp = (la + 70) >> 3;

  // cost regs: cc = current group (rows 8g+k-ln), cn = next group prefetch
  float2 cc[8], cn[8];
  #pragma unroll
  for (int k = 0; k < 8; ++k) {
    int rr = k - ln; rr = rr < 0 ? 0 : (rr > 511 ? 511 : rr);
    cc[k] = *(const float2*)(Cp + (size_t)rr * TT);
  }
  float bb[8];

  for (int g = 0; g < ngrp; ++g) {
    if (q > 0) {
      int need = 8 * g + 9; if (need > la) need = la;
      while (*(volatile int*)&flags[q - 1] < need) __builtin_amdgcn_s_sleep(1);
      asm volatile("s_waitcnt lgkmcnt(0)" ::: "memory");
      #pragma unroll
      for (int k = 0; k < 8; ++k) bb[k] = bufB[q - 1][8 * g + 1 + k];
      if (g == 0) {
        float nl0 = bufB[q - 1][0];
        if (ln == 0) NL = nl0;
      }
    }
    // prefetch cost for next group (clamped rows; stays in flight this group)
    #pragma unroll
    for (int k = 0; k < 8; ++k) {
      int rr = 8 * (g + 1) + k - ln; rr = rr < 0 ? 0 : (rr > 511 ? 511 : rr);
      cn[k] = *(const float2*)(Cp + (size_t)rr * TT);
    }
    if (g >= 8 && g < 64) {
      // ---- STEADY: r = 8g+k-ln in [1,511] for every lane -> no act guard ----
      #pragma unroll
      for (int k = 0; k < 8; ++k) {
        int r = 8 * g + k - ln;
        float v0 = dpcell(cc[k].x, NLd, U0, NL);
        float v1 = dpcell(cc[k].y, U0, U1, v0);
        if (isT & (r == rt)) res = par ? v1 : v0;
        NLd = NL; U0 = v0; U1 = v1; v1s = v1;
        if (q < 3 && ln == 63) {
          bufB[q][r] = v1;
          if ((r & 7) == 0) {
            // order bufB write before flag write; LDS-only wait (no vmcnt
            // drain). For lane63, r%8==0 occurs at k=7 — group end.
            asm volatile("s_waitcnt lgkmcnt(0)" ::: "memory");
            *(volatile int*)&flags[q] = r + 1;
          }
        }
        float nb = wave_shr1(v1s);
        if (ln == 0) nb = (q == 0) ? BIGC : bb[k];
        NL = nb;
      }
    } else {
      // ---- fill / drain: per-lane act guard as before ----
      #pragma unroll
      for (int k = 0; k < 8; ++k) {
        int r = 8 * g + k - ln;
        bool act = ((unsigned)r < 512u);
        if (act) {
          float v0 = dpcell(cc[k].x, NLd, U0, NL);
          float v1 = dpcell(cc[k].y, U0, U1, v0);
          if (isT & (r == rt)) res = par ? v1 : v0;
          NLd = NL; U0 = v0; U1 = v1; v1s = v1;
          if (q < 3 && ln == 63) {
            bufB[q][r] = v1;
            if ((r & 7) == 0) {
              asm volatile("s_waitcnt lgkmcnt(0)" ::: "memory");
              *(volatile int*)&flags[q] = r + 1;
            }
          }
        }
        float nb = wave_shr1(v1s);
        if (ln == 0) nb = (q == 0) ? BIGC : bb[k];
        NL = nb;
      }
    }
    #pragma unroll
    for (int k = 0; k < 8; ++k) cc[k] = cn[k];
  }
  if (q < 3 && ln == 63) {
    asm volatile("s_waitcnt lgkmcnt(0)" ::: "memory");
    *(volatile int*)&flags[q] = 512;   // release any remaining pollers
  }
  if (isT) sdt[blk] = res * USCALE;
}

// ---------------------------------------------------------------------------
// Kernel 4: final combine. block 640 = 10 waves; waves 0..8: one MMD pair each;
// wave 9: triplet losses; thread 0 writes the scalar.
// ---------------------------------------------------------------------------
__global__ __launch_bounds__(640) void final_kernel(const float* __restrict__ sdt,
                                                    const int* __restrict__ lens,
                                                    const float* __restrict__ gram,
                                                    float* __restrict__ out) {
  __shared__ float partial[16];
  int t = threadIdx.x, wave = t >> 6, lane = t & 63;
  if (wave < 9) {
    const int piA[9] = {0, 0, 0, 1, 1, 2, 2, 3, 3};
    const int pjA[9] = {1, 2, 3, 2, 3, 1, 3, 1, 2};
    int P = piA[wave], Q = pjA[wave];
    float s1 = 0.f;
    for (int c = lane; c < 484; c += 64) {
      int i = c / 22, jj = c - (c / 22) * 22;
      int gi = (i < 11) ? P * 11 + i : Q * 11 + (i - 11);
      int gj = (jj < 11) ? P * 11 + jj : Q * 11 + (jj - 11);
      s1 += gram[gi * 44 + gi] + gram[gj * 44 + gj] - 2.f * gram[gi * 44 + gj];
    }
    for (int off = 32; off > 0; off >>= 1) s1 += __shfl_down(s1, off);
    s1 = __shfl(s1, 0);
    float bw = s1 / 462.0f * 0.25f;     // /(ns^2-ns) then / KMUL^(KNUM//2)=4
    float inv[5];
    float b = bw;
    #pragma unroll
    for (int qq = 0; qq < 5; ++qq) { inv[qq] = -1.0f / b; b *= 2.0f; }
    float s2 = 0.f;
    for (int c = lane; c < 484; c += 64) {
      int i = c / 22, jj = c - (c / 22) * 22;
      int gi = (i < 11) ? P * 11 + i : Q * 11 + (i - 11);
      int gj = (jj < 11) ? P * 11 + jj : Q * 11 + (jj - 11);
      float l2 = gram[gi * 44 + gi] + gram[gj * 44 + gj] - 2.f * gram[gi * 44 + gj];
      float kk = 0.f;
      #pragma unroll
      for (int qq = 0; qq < 5; ++qq) kk += __expf(l2 * inv[qq]);
      float sgn = ((i < 11) == (jj < 11)) ? 1.0f : -1.0f;
      s2 += sgn * kk;
    }
    for (int off = 32; off > 0; off >>= 1) s2 += __shfl_down(s2, off);
    if (lane == 0) partial[wave] = s2 / 121.0f;
  } else {
    float term = 0.f;
    if (wave == 9 && lane < 4) {
      int w = lane;
      float L0 = (float)lens[w * STP];
      float dist[15];
      for (int qq = 0; qq < 15; ++qq)
        dist[qq] = sdt[w * NPJ + qq] / (L0 + (float)lens[w * STP + 1 + qq]);
      float ca = 0.f, cb = 0.f;
      for (int a = 0; a < 6; ++a) ca += dist[a];
      ca *= (1.0f / 6.0f);
      for (int bq = 6; bq < 11; ++bq) cb += dist[bq];
      cb *= (1.0f / 5.0f);
      float lksum = 0.f; int nz = 0;
      for (int a = 0; a < 6; ++a)
        for (int bq = 6; bq < 15; ++bq) {
          float x = dist[a] + 1.0f - dist[bq];   // MARGIN = 1.0
          if (x > 0.f) { lksum += x; nz += 1; }
        }
      float intra = 0.f;
      for (int a = 0; a < 6; ++a) intra += dist[a] - ca;
      float inter = fmaxf(0.f, 1.0f - fabsf(ca - cb));  // BETA = 1.0
      term = lksum / (float)(nz + 1) + intra * 0.1f + inter * 0.1f;  // P=R=0.1
    }
    if (wave == 9) {
      term += __shfl_down(term, 1);
      term += __shfl_down(term, 2);
      if (lane == 0) partial[9] = term * 0.25f;   // mean over NW=4
    }
  }
  __syncthreads();
  if (t == 0) {
    float mx = 0.0f;                               // zero-pad in the max
    for (int p = 0; p < 9; ++p) mx = fmaxf(mx, partial[p]);
    out[0] = partial[9] + 0.01f * mx;              // ALPHA = 0.01
  }
}

// ---------------------------------------------------------------------------
extern "C" void kernel_launch(void* const* d_in, const int* in_sizes, int n_in,
                              void* d_out, int out_size, void* d_ws, size_t ws_size,
                              hipStream_t stream) {
  const float* data = (const float*)d_in[0];
  const int* lens = (const int*)d_in[1];
  float* out = (float*)d_out;

  float* sdtb  = (float*)d_ws;                      // 60 floats
  float* gramb = sdtb + 64;                         // 44*44 floats
  float* costb = (float*)((char*)d_ws + 8192);      // cost chunks

  size_t avail = (ws_size > 8192) ? (ws_size - 8192) : 0;
  int chunk = (int)(avail / ((size_t)CMAT * sizeof(float)));
  if (chunk < 1) chunk = 1;
  if (chunk > NBLK) chunk = NBLK;

  bool first = true;
  for (int base = 0; base < NBLK; base += chunk) {
    int n = NBLK - base;
    if (n > chunk) n = chunk;
    cost_kernel<<<dim3(4, 4, n), 256, 0, stream>>>(data, lens, costb, base);
    int extra = first ? 121 : 0;   // fuse gram onto otherwise-idle CUs
    dp_gram_kernel<<<n + extra, 256, 0, stream>>>(costb, lens, data, sdtb, gramb, base, n);
    first = false;
  }
  final_kernel<<<1, 640, 0, stream>>>(sdtb, lens, gramb, out);
}